// Round 19
// baseline (488.276 us; speedup 1.0000x reference)
//
#include <hip/hip_runtime.h>
#include <hip/hip_bf16.h>
#include <stdint.h>

#define BB 8
#define LL 4096
#define DD 64
#define KTW 128
#define NTW (LL / KTW)       // 32 tiles, both passes

typedef short bf16x8 __attribute__((ext_vector_type(8)));
typedef float f32x4 __attribute__((ext_vector_type(4)));

#define QSCALE 0.1803368801111204f   // (1/8)*log2(e): folds scale + exp->exp2

__device__ inline short f2bfs(float x) {
    __hip_bfloat16 h = __float2bfloat16(x);
    return __builtin_bit_cast(short, h);
}

__device__ inline bf16x8 pack8v(f32x4 a, f32x4 b) {
    bf16x8 r;
    r[0] = f2bfs(a[0]); r[1] = f2bfs(a[1]); r[2] = f2bfs(a[2]); r[3] = f2bfs(a[3]);
    r[4] = f2bfs(b[0]); r[5] = f2bfs(b[1]); r[6] = f2bfs(b[2]); r[7] = f2bfs(b[3]);
    return r;
}

__device__ inline int swzK(int r) { return (r & 3) | (((r >> 3) & 1) << 2); }
__device__ inline int swzV(int r) { return (r & 7) ^ ((r >> 3) & 7); }

// Raw barrier: flush own LDS ops, leave global/DMA loads in flight.
__device__ inline void wg_barrier() {
    asm volatile("s_waitcnt lgkmcnt(0)" ::: "memory");
    __builtin_amdgcn_s_barrier();
    __builtin_amdgcn_sched_barrier(0);
}

// Direct global->LDS DMA, 16B per lane. LDS dest = wave-uniform base + lane*16.
__device__ inline void gl_lds16(const ushort* g, ushort* l) {
    __builtin_amdgcn_global_load_lds((const __attribute__((address_space(1))) void*)g,
                                     (__attribute__((address_space(3))) void*)l, 16, 0, 0);
}

__global__ void detect_mask_kernel(const uint32_t* __restrict__ w, uint32_t* __restrict__ flag) {
    __shared__ int nonbin;
    if (threadIdx.x == 0) nonbin = 0;
    __syncthreads();
    int bad = 0;
    for (int i = threadIdx.x; i < 4096; i += 256) bad |= (w[i] > 1u) ? 1 : 0;
    if (bad) atomicOr(&nonbin, 1);
    __syncthreads();
    if (threadIdx.x == 0) *flag = (uint32_t)(nonbin != 0);
}

// K -> bf16, elementwise (8 elems/thread).
__global__ void convert_k_kernel(const float* __restrict__ src, ushort* __restrict__ dst) {
    const int i = blockIdx.x * 256 + threadIdx.x;
    f32x4 a = *(const f32x4*)(src + (size_t)i * 8);
    f32x4 b = *(const f32x4*)(src + (size_t)i * 8 + 4);
    *(bf16x8*)(dst + (size_t)i * 8) = pack8v(a, b);
}

// V -> transposed bf16 Vt[b][d][k] via LDS tile.
__global__ void convert_vt_kernel(const float* __restrict__ v, ushort* __restrict__ vt) {
    __shared__ alignas(16) float Lt[64][68];
    const int kt = blockIdx.x, b = blockIdx.y;
    const int tid = (int)threadIdx.x;
    const int r = tid >> 2, c4 = tid & 3;
    const float* vb = v + ((size_t)b * LL + kt * 64) * DD;
    #pragma unroll
    for (int j = 0; j < 4; ++j)
        *(f32x4*)&Lt[r][c4 * 16 + j * 4] = *(const f32x4*)(vb + (size_t)r * DD + c4 * 16 + j * 4);
    __syncthreads();
    ushort* vout = vt + (size_t)b * DD * LL + (size_t)r * LL + kt * 64 + c4 * 16;
    bf16x8 o0, o1;
    #pragma unroll
    for (int j = 0; j < 8; ++j) o0[j] = f2bfs(Lt[c4 * 16 + j][r]);
    #pragma unroll
    for (int j = 0; j < 8; ++j) o1[j] = f2bfs(Lt[c4 * 16 + 8 + j][r]);
    *(bf16x8*)vout = o0;
    *(bf16x8*)(vout + 8) = o1;
}

// Block = 64 q-rows of one batch, 512 threads / 8 waves (rg=w&3 q-group,
// ch=w>>2 64-k half of the 128-wide tile). KT=128: 64 barriers/pass (half of
// R18), 16 MFMA + 16 exp2 per wave per barrier quantum. All staging is DMA
// (global_load_lds) + pinned asm mask loads, double-buffered, with op-exact
// counted vmcnt (pass-2 counts its own stores: 4 loads + 4 stores/tile).
__global__ __launch_bounds__(512, 4) void fused_attn_kernel(
    const float* __restrict__ qg, const ushort* __restrict__ kbf,
    const ushort* __restrict__ vtb, const void* __restrict__ maskv,
    const uint32_t* __restrict__ flagp,
    float* __restrict__ attn, float* __restrict__ outp)
{
    __shared__ alignas(16) ushort KB[4][KTW * 64];   // 4 x 16 KB: K {0,1}, V^T {2,3}
    __shared__ float Rs[128];

    const int tid = (int)threadIdx.x;
    const int w   = tid >> 6, l = tid & 63;
    const int lr  = l & 15, lg = l >> 4;
    const int rg  = w & 3, ch = w >> 2;
    const int id  = (int)blockIdx.x;     // id = qt*8 + b
    const int b   = id & 7;
    const int q0  = (id >> 3) * 64;
    const bool mbyte = (*flagp != 0);

    const ushort* kb  = kbf + (size_t)b * LL * DD;   // bf16 K [k][d]
    const ushort* vtg = vtb + (size_t)b * DD * LL;   // bf16 V^T [d][k]

    const int qrow = q0 + 16 * rg + lr;
    const uint8_t* mrow8  = (const uint8_t*)maskv + (size_t)b * LL * LL + (size_t)qrow * LL + ch * 64 + lg * 8;
    const int*     mrow32 = (const int*)maskv     + (size_t)b * LL * LL + (size_t)qrow * LL + ch * 64 + lg * 8;
    float* arow = attn + (size_t)b * LL * LL + (size_t)qrow * LL + ch * 64 + lg * 8;

    bf16x8 qf0, qf1;
    {
        const float* qp = qg + (size_t)(b * LL + qrow) * DD + lg * 8;
        qf0 = pack8v(*(const f32x4*)(qp)      * QSCALE, *(const f32x4*)(qp + 4)  * QSCALE);
        qf1 = pack8v(*(const f32x4*)(qp + 32) * QSCALE, *(const f32x4*)(qp + 36) * QSCALE);
    }

    // ---------- DMA staging lanes ----------
    const int drK = w * 8 + (l >> 3), dcK = l & 7;
    const int sK0 = dcK ^ swzK(drK);            // swzK(r+64)==swzK(r)
    const int dV  = l >> 4, cV = l & 15;

    auto dmaK = [&](int kt, int slot) {         // 128x64 bf16 K tile, 2 DMA/lane
        gl_lds16(kb + ((size_t)(kt * KTW + drK) << 6) + 8 * sK0,      &KB[slot][(w * 8) * 64]);
        gl_lds16(kb + ((size_t)(kt * KTW + 64 + drK) << 6) + 8 * sK0, &KB[slot][(w * 8 + 64) * 64]);
    };
    auto dmaV = [&](int kt, int slot) {         // 64x128 bf16 V^T tile, 2 DMA/lane
        const int d0 = w * 8 + dV, d1 = w * 8 + 4 + dV;
        gl_lds16(vtg + (size_t)d0 * LL + kt * KTW + 8 * (cV ^ swzV(d0)), &KB[2 + slot][(w * 8) * 128]);
        gl_lds16(vtg + (size_t)d1 * LL + kt * KTW + 8 * (cV ^ swzV(d1)), &KB[2 + slot][(w * 8 + 4) * 128]);
    };
    unsigned long long mA0 = 0, mA1 = 0, mB0 = 0, mB1 = 0;
    #define MLOAD(dst, off) { unsigned long long a_ = (unsigned long long)(uintptr_t)(mrow8 + (off)); \
        asm volatile("global_load_dwordx2 %0, %1, off" : "=v"(dst) : "v"(a_) : "memory"); }

    // ================= pass 1: rowsums + unnormalized PV (P in regs) =================
    float rsum = 0.f;
    f32x4 oacc[4];
    #pragma unroll
    for (int g = 0; g < 4; ++g) { f32x4 z = {0.f, 0.f, 0.f, 0.f}; oacc[g] = z; }

    auto body1 = [&](int slot, unsigned long long mu0, unsigned long long mu1, int kt) {
        bf16x8 pa0, pa1;
        __builtin_amdgcn_s_setprio(1);
        #pragma unroll
        for (int s = 0; s < 2; ++s) {
            #pragma unroll
            for (int n = 0; n < 2; ++n) {
                const int krow = ch * 64 + s * 32 + ((lr >> 2) << 3) + (n << 2) + (lr & 3);
                bf16x8 k0 = *(const bf16x8*)&KB[slot][krow * 64 + ((lg       ^ swzK(krow)) << 3)];
                bf16x8 k1 = *(const bf16x8*)&KB[slot][krow * 64 + (((4 + lg) ^ swzK(krow)) << 3)];
                f32x4 c = {0.f, 0.f, 0.f, 0.f};
                c = __builtin_amdgcn_mfma_f32_16x16x32_bf16(k0, qf0, c, 0, 0, 0);
                c = __builtin_amdgcn_mfma_f32_16x16x32_bf16(k1, qf1, c, 0, 0, 0);
                int4 mi = {0, 0, 0, 0};
                if (!mbyte) mi = *(const int4*)(mrow32 + kt * KTW + s * 32 + n * 4);
                #pragma unroll
                for (int j = 0; j < 4; ++j) {
                    const int t = n * 4 + j;
                    int mk;
                    if (mbyte) mk = (int)(((s ? mu1 : mu0) >> (8 * t)) & 0xffu);
                    else       mk = (j == 0) ? mi.x : (j == 1) ? mi.y : (j == 2) ? mi.z : mi.w;
                    const float pv = mk ? 0.f : exp2f(c[j]);
                    rsum += pv;
                    if (s) pa1[t] = f2bfs(pv); else pa0[t] = f2bfs(pv);
                }
            }
        }
        #pragma unroll
        for (int g = 0; g < 4; ++g) {
            const int d = g * 16 + lr;
            bf16x8 vf0 = *(const bf16x8*)&KB[2 + slot][d * 128 + (((ch * 8 + lg)     ^ swzV(d)) << 3)];
            oacc[g] = __builtin_amdgcn_mfma_f32_16x16x32_bf16(pa0, vf0, oacc[g], 0, 0, 0);
            bf16x8 vf1 = *(const bf16x8*)&KB[2 + slot][d * 128 + (((ch * 8 + 4 + lg) ^ swzV(d)) << 3)];
            oacc[g] = __builtin_amdgcn_mfma_f32_16x16x32_bf16(pa1, vf1, oacc[g], 0, 0, 0);
        }
        __builtin_amdgcn_s_setprio(0);
    };

    // prologue: tiles 0,1 in flight (6 vm-ops per tile when mbyte)
    dmaK(0, 0); dmaV(0, 0); if (mbyte) { MLOAD(mA0, 0); MLOAD(mA1, 32); }
    dmaK(1, 1); dmaV(1, 1); if (mbyte) { MLOAD(mB0, KTW); MLOAD(mB1, KTW + 32); }
    #pragma unroll 1
    for (int kt = 0; kt < NTW; kt += 2) {
        if (mbyte) asm volatile("s_waitcnt vmcnt(6)" ::: "memory");
        else       asm volatile("s_waitcnt vmcnt(0)" ::: "memory");
        __builtin_amdgcn_sched_barrier(0);
        wg_barrier();
        body1(0, mA0, mA1, kt);
        wg_barrier();
        {   const int nx = (kt + 2) & (NTW - 1);
            dmaK(nx, 0); dmaV(nx, 0);
            if (mbyte) { MLOAD(mA0, nx * KTW); MLOAD(mA1, nx * KTW + 32); } }
        if (mbyte) asm volatile("s_waitcnt vmcnt(6)" ::: "memory");
        else       asm volatile("s_waitcnt vmcnt(0)" ::: "memory");
        __builtin_amdgcn_sched_barrier(0);
        wg_barrier();
        body1(1, mB0, mB1, kt + 1);
        wg_barrier();
        {   const int nx = (kt + 3) & (NTW - 1);
            dmaK(nx, 1); dmaV(nx, 1);
            if (mbyte) { MLOAD(mB0, nx * KTW); MLOAD(mB1, nx * KTW + 32); } }
    }
    asm volatile("s_waitcnt vmcnt(0)" ::: "memory");   // drain wrapped stragglers

    rsum += __shfl_xor(rsum, 16, 64);
    rsum += __shfl_xor(rsum, 32, 64);
    if (lg == 0) Rs[ch * 64 + 16 * rg + lr] = rsum;
    __syncthreads();
    const float rinv = 1.0f / (Rs[16 * rg + lr] + Rs[64 + 16 * rg + lr]);

    // epilogue: combine ch halves of O via retired KB region
    float* OutL = (float*)KB;
    if (ch == 1) {
        #pragma unroll
        for (int g = 0; g < 4; ++g)
            #pragma unroll
            for (int j = 0; j < 4; ++j)
                OutL[rg * 1088 + (lg * 4 + j) * 68 + g * 16 + lr] = oacc[g][j];
    }
    __syncthreads();
    if (ch == 0) {
        #pragma unroll
        for (int j = 0; j < 4; ++j) {
            const int ql = 16 * rg + lg * 4 + j;
            const float ri = 1.0f / (Rs[ql] + Rs[64 + ql]);
            const size_t orow = (size_t)(b * LL + q0 + ql) * DD;
            #pragma unroll
            for (int g = 0; g < 4; ++g)
                outp[orow + g * 16 + lr] = (oacc[g][j] + OutL[rg * 1088 + (lg * 4 + j) * 68 + g * 16 + lr]) * ri;
        }
    }
    __syncthreads();   // OutL reads complete BEFORE pass-2 DMA restages KB

    // ================= pass 2: recompute + attn write (KT=128, store-aware waits) =================
    auto body2 = [&](int slot, unsigned long long mu0, unsigned long long mu1, int kt) {
        __builtin_amdgcn_s_setprio(1);
        #pragma unroll
        for (int s = 0; s < 2; ++s) {
            #pragma unroll
            for (int n = 0; n < 2; ++n) {
                const int krow = ch * 64 + s * 32 + ((lr >> 2) << 3) + (n << 2) + (lr & 3);
                bf16x8 k0 = *(const bf16x8*)&KB[slot][krow * 64 + ((lg       ^ swzK(krow)) << 3)];
                bf16x8 k1 = *(const bf16x8*)&KB[slot][krow * 64 + (((4 + lg) ^ swzK(krow)) << 3)];
                f32x4 c = {0.f, 0.f, 0.f, 0.f};
                c = __builtin_amdgcn_mfma_f32_16x16x32_bf16(k0, qf0, c, 0, 0, 0);
                c = __builtin_amdgcn_mfma_f32_16x16x32_bf16(k1, qf1, c, 0, 0, 0);
                int4 mi = {0, 0, 0, 0};
                if (!mbyte) mi = *(const int4*)(mrow32 + kt * KTW + s * 32 + n * 4);
                f32x4 pv;
                #pragma unroll
                for (int j = 0; j < 4; ++j) {
                    const int t = n * 4 + j;
                    int mk;
                    if (mbyte) mk = (int)(((s ? mu1 : mu0) >> (8 * t)) & 0xffu);
                    else       mk = (j == 0) ? mi.x : (j == 1) ? mi.y : (j == 2) ? mi.z : mi.w;
                    pv[j] = mk ? 0.f : exp2f(c[j]) * rinv;
                }
                *(f32x4*)(arow + kt * KTW + s * 32 + n * 4) = pv;
            }
        }
        __builtin_amdgcn_s_setprio(0);
    };

    dmaK(0, 0); if (mbyte) { MLOAD(mA0, 0); MLOAD(mA1, 32); }
    dmaK(1, 1); if (mbyte) { MLOAD(mB0, KTW); MLOAD(mB1, KTW + 32); }
    #pragma unroll 1
    for (int kt = 0; kt < NTW; kt += 2) {
        if (mbyte) asm volatile("s_waitcnt vmcnt(4)" ::: "memory");
        else       asm volatile("s_waitcnt vmcnt(0)" ::: "memory");
        __builtin_amdgcn_sched_barrier(0);
        wg_barrier();
        body2(0, mA0, mA1, kt);
        wg_barrier();
        {   const int nx = (kt + 2) & (NTW - 1);
            dmaK(nx, 0);
            if (mbyte) { MLOAD(mA0, nx * KTW); MLOAD(mA1, nx * KTW + 32); } }
        if (mbyte) asm volatile("s_waitcnt vmcnt(4)" ::: "memory");
        else       asm volatile("s_waitcnt vmcnt(0)" ::: "memory");
        __builtin_amdgcn_sched_barrier(0);
        wg_barrier();
        body2(1, mB0, mB1, kt + 1);
        wg_barrier();
        {   const int nx = (kt + 3) & (NTW - 1);
            dmaK(nx, 1);
            if (mbyte) { MLOAD(mB0, nx * KTW); MLOAD(mB1, nx * KTW + 32); } }
    }
    asm volatile("s_waitcnt vmcnt(0)" ::: "memory");   // drain before block exit
}

extern "C" void kernel_launch(void* const* d_in, const int* in_sizes, int n_in,
                              void* d_out, int out_size, void* d_ws, size_t ws_size,
                              hipStream_t stream) {
    const float* q = (const float*)d_in[0];
    const float* k = (const float*)d_in[1];
    const float* v = (const float*)d_in[2];
    const void* mask = d_in[3];
    float* attn = (float*)d_out;
    float* outp = attn + (size_t)BB * LL * LL;
    uint32_t* flagp = (uint32_t*)d_ws;
    ushort* kbf = (ushort*)((char*)d_ws + 4096);                 // bf16 K   [b][k][d], 4 MB
    ushort* vtb = kbf + (size_t)BB * LL * DD;                    // bf16 V^T [b][d][k], 4 MB

    detect_mask_kernel<<<1, 256, 0, stream>>>((const uint32_t*)mask, flagp);
    convert_k_kernel<<<dim3(BB * LL * DD / 8 / 256), 256, 0, stream>>>(k, kbf);
    convert_vt_kernel<<<dim3(LL / 64, BB), 256, 0, stream>>>(v, vtb);
    fused_attn_kernel<<<dim3((LL / 64) * BB), 512, 0, stream>>>(q, kbf, vtb, mask, flagp, attn, outp);
}